// Round 9
// baseline (95.747 us; speedup 1.0000x reference)
//
#include <hip/hip_runtime.h>
#include <hip/hip_bf16.h>
#include <stdint.h>

#define NR   4096
#define DIM  1024
#define NE   8
#define BM   128
#define BN   128
#define BK   32

typedef __attribute__((ext_vector_type(8))) short  bf16x8;
typedef __attribute__((ext_vector_type(8))) ushort u16x8;
typedef __attribute__((ext_vector_type(4))) float  f32x4;

__device__ __forceinline__ ushort f2bf(float f) {
    union { __hip_bfloat16 h; ushort u; } cv;
    cv.h = __float2bfloat16(f);   // RNE
    return cv.u;
}

__device__ __forceinline__ void gload16(const void* g, void* l) {
    __builtin_amdgcn_global_load_lds(
        (const __attribute__((address_space(1))) unsigned int*)g,
        (__attribute__((address_space(3))) unsigned int*)l, 16, 0, 0);
}

// ---------------- K1: WT transpose (blocks 0..7) + zero out (blocks 8..519) --
__global__ __launch_bounds__(256)
void k1_prep(const float* __restrict__ Wg, const float* __restrict__ Wn,
             float* __restrict__ WT, float* __restrict__ out) {
    const int tid = threadIdx.x;
    if (blockIdx.x < 8) {
        const int k    = blockIdx.x * 128 + (tid >> 1);
        const int half = tid & 1;                     // 0 = Wg, 1 = Wn
        const float* src = half ? Wn : Wg;
        const float4* s4 = (const float4*)(src + (size_t)k * NE);
        float4 a = s4[0], b = s4[1];
        float* d = WT + (size_t)half * 8 * DIM;
        d[(size_t)0 * DIM + k] = a.x; d[(size_t)1 * DIM + k] = a.y;
        d[(size_t)2 * DIM + k] = a.z; d[(size_t)3 * DIM + k] = a.w;
        d[(size_t)4 * DIM + k] = b.x; d[(size_t)5 * DIM + k] = b.y;
        d[(size_t)6 * DIM + k] = b.z; d[(size_t)7 * DIM + k] = b.w;
    } else {
        const int vb = blockIdx.x - 8;                // 0..511
        float4 z = {0.f, 0.f, 0.f, 0.f};
        for (int i = vb * 256 + tid; i < NR * DIM / 4; i += 512 * 256)
            ((float4*)out)[i] = z;
    }
}

// ---------------- K2: We convert+transpose (blocks 0..2047) | gate (2048..3071)
__global__ __launch_bounds__(256)
void k2_main(const float* __restrict__ We, ushort* __restrict__ WeT,
             const float* __restrict__ x, const float* __restrict__ noise,
             const float* __restrict__ WT, ushort* __restrict__ xbf,
             uint32_t* __restrict__ eid, float2* __restrict__ wpair) {
    __shared__ float smem[64 * 68];                   // 17.4 KB, both roles
    const int tid = threadIdx.x;
    if (blockIdx.x < 2048) {
        // ---- conv role: We [e][k][c] f32 -> WeT [e][c][k] bf16 ----
        const int b  = blockIdx.x;                    // e*256 + kt*16 + ct
        const int e  = b >> 8, kt = (b >> 4) & 15, ct = b & 15;
        const float* src = We + ((size_t)e * DIM + (size_t)kt * 64) * DIM + ct * 64;
#pragma unroll
        for (int j = 0; j < 4; ++j) {
            int idx = tid + j * 256;
            int r = idx >> 4, c4 = idx & 15;
            *(float4*)&smem[r * 68 + c4 * 4] = *(const float4*)(src + (size_t)r * DIM + c4 * 4);
        }
        __syncthreads();
        ushort* dst = WeT + ((size_t)e * DIM + (size_t)ct * 64) * DIM + kt * 64;
#pragma unroll
        for (int j = 0; j < 2; ++j) {
            int u = tid + j * 256;
            int c = u >> 3, ch = u & 7;
            ushort tmp[8];
#pragma unroll
            for (int q = 0; q < 8; ++q) tmp[q] = f2bf(smem[(ch * 8 + q) * 68 + c]);
            *(u16x8*)(dst + (size_t)c * DIM + ch * 8) = *(u16x8*)tmp;
        }
    } else {
        // ---- gate role: one wave per row, no atomics ----
        const int w = tid >> 6, l = tid & 63;
        const int row = (blockIdx.x - 2048) * 4 + w;
        const float* xr = x + (size_t)row * DIM;

        float4 xv[4];
#pragma unroll
        for (int q = 0; q < 4; ++q) xv[q] = *(const float4*)(xr + q * 256 + l * 4);
#pragma unroll
        for (int q = 0; q < 4; ++q) {
            ushort4 xb;
            xb.x = f2bf(xv[q].x); xb.y = f2bf(xv[q].y);
            xb.z = f2bf(xv[q].z); xb.w = f2bf(xv[q].w);
            *(ushort4*)(xbf + (size_t)row * DIM + q * 256 + l * 4) = xb;
        }

        float acc[16];
#pragma unroll
        for (int u = 0; u < 16; ++u) {
            const float* wr_ = WT + (size_t)u * DIM + l * 4;
            float s = 0.f;
#pragma unroll
            for (int q = 0; q < 4; ++q) {
                float4 wv = *(const float4*)(wr_ + q * 256);
                s += xv[q].x * wv.x + xv[q].y * wv.y + xv[q].z * wv.z + xv[q].w * wv.w;
            }
            acc[u] = s;
        }
#pragma unroll
        for (int u = 0; u < 16; ++u) smem[(w * 64 + l) * 17 + u] = acc[u];
        asm volatile("s_waitcnt lgkmcnt(0)" ::: "memory");
        const int c = l >> 4, u = l & 15;
        float v = 0.f;
#pragma unroll
        for (int i = 0; i < 16; ++i) v += smem[(w * 64 + c * 16 + i) * 17 + u];
        v += __shfl_xor(v, 16, 64);
        v += __shfl_xor(v, 32, 64);

        const int e = l & 7;
        float ag = __shfl(v, e, 64);
        float an = __shfl(v, e + 8, 64);
        float sp = (an > 0.f) ? (an + log1pf(expf(-an))) : log1pf(expf(an));
        float H  = ag + noise[e] * sp;

        float Hh[8];
#pragma unroll
        for (int k = 0; k < 8; ++k) Hh[k] = __shfl(H, k, 64);
        if (l == 0) {
            int e0 = 0; float v0 = Hh[0];
#pragma unroll
            for (int k = 1; k < 8; ++k) if (Hh[k] > v0) { v0 = Hh[k]; e0 = k; }
            int e1 = -1; float v1 = 0.f;
#pragma unroll
            for (int k = 0; k < 8; ++k)
                if (k != e0 && (e1 < 0 || Hh[k] > v1)) { v1 = Hh[k]; e1 = k; }
            float rr = expf(v1 - v0);
            float w0 = 1.f / (1.f + rr), w1 = 1.f - w0;
            eid[row] = (uint32_t)e0 | ((uint32_t)e1 << 8);
            float2 wp; wp.x = w0; wp.y = w1;
            wpair[row] = wp;
        }
    }
}

// ---------------- bucket build: MERGED per-expert buckets (8) ---------------
// row joins bucket e if e0==e (weight w0) or e1==e (weight w1); stable order.
__global__ __launch_bounds__(1024)
void bucket_build(const uint32_t* __restrict__ eid, const float2* __restrict__ wpair,
                  int* __restrict__ cnt, int* __restrict__ idxl, float* __restrict__ wl) {
    const int ex = blockIdx.x;              // 0..7
    __shared__ int base;
    __shared__ int wsum[16];
    if (threadIdx.x == 0) base = 0;
    const int wid = threadIdx.x >> 6, lane = threadIdx.x & 63;
    int* bidx = idxl + (size_t)ex * NR;
    float* bwl = wl + (size_t)ex * NR;

    for (int c0 = 0; c0 < NR; c0 += 1024) {
        const int row = c0 + threadIdx.x;
        const uint32_t em = eid[row];
        const bool m0 = (int)(em & 255u) == ex;
        const bool m1 = (int)((em >> 8) & 255u) == ex;
        const bool m = m0 || m1;
        const unsigned long long bal = __ballot(m);
        if (lane == 0) wsum[wid] = __popcll(bal);
        __syncthreads();
        int wbase = base;
        for (int i = 0; i < wid; ++i) wbase += wsum[i];
        const int pos = wbase + __popcll(bal & ((1ull << lane) - 1ull));
        if (m) {
            bidx[pos] = row;
            float2 wp = wpair[row];
            bwl[pos]  = m0 ? wp.x : wp.y;
        }
        __syncthreads();
        if (threadIdx.x == 0) {
            int s = 0;
#pragma unroll
            for (int i = 0; i < 16; ++i) s += wsum[i];
            base += s;
        }
        __syncthreads();
    }
    if (threadIdx.x == 0) cnt[ex] = base;
}

// ---------------- grouped expert GEMM: phase-interleaved, ring-4, counted ----
// 128x128 tile, BK=32, 4 waves. Per K-tile: 2 phases, each
// {ds_read frags | issue 2 gloads(t+3) | barrier | lgkm(0) | 8 MFMA | barrier};
// vmcnt(8) counted once per tile (2 tiles always in flight). 2 blocks/CU.
__global__ __launch_bounds__(256, 2)
void moe_gemm(const ushort* __restrict__ xbf, const ushort* __restrict__ WeT,
              const float* __restrict__ be, const int* __restrict__ cnt,
              const int* __restrict__ idxl, const float* __restrict__ wl,
              float* __restrict__ out) {
    __shared__ ushort lds[4][256][BK];    // 4 bufs x (A rows 0..127, B rows 128..255)

    const int q8 = gridDim.x >> 3;
    const int W  = (blockIdx.x & 7) * q8 + (blockIdx.x >> 3);
    const int item = W >> 3, cT = W & 7;

    int bucket = -1, tile = 0, accp = 0;
#pragma unroll
    for (int b = 0; b < NE; ++b) {
        int t = (cnt[b] + BM - 1) >> 7;
        if (bucket < 0 && item < accp + t) { bucket = b; tile = item - accp; }
        accp += t;
    }
    if (bucket < 0) return;
    const int count  = cnt[bucket];
    const int nrowsv = min(BM, count - tile * BM);
    const int e  = bucket;
    const int c0 = cT * BN;
    const int*   rows = idxl + (size_t)bucket * NR + tile * BM;
    const float* wrow = wl   + (size_t)bucket * NR + tile * BM;

    const int tid = threadIdx.x, wid = tid >> 6, lane = tid & 63;
    const int l16 = lane & 15, lhi = lane >> 4;
    const int wr = (wid >> 1) * 64, wc = (wid & 1) * 64;

    // staging: unit u = g*256 + tid -> row = u>>2, chunk = lane&3 (linear LDS);
    // source chunk = (lane&3) ^ f(row), f(r) = (r ^ (r>>2)) & 3 = ((lane>>2)^(lane>>4))&3
    const int fs   = ((lane >> 2) ^ (lane >> 4)) & 3;
    const int csrc = ((lane & 3) ^ fs) * 8;                    // ushort offset
    const ushort* aptr[2];
    const ushort* bptr[2];
#pragma unroll
    for (int g = 0; g < 2; ++g) {
        int r = g * 64 + wid * 16 + (lane >> 2);
        aptr[g] = xbf + (size_t)rows[min(r, nrowsv - 1)] * DIM + csrc;
        int c = c0 + g * 64 + wid * 16 + (lane >> 2);
        bptr[g] = WeT + ((size_t)(e * DIM + c)) * DIM + csrc;
    }

    f32x4 acc[4][4];
#pragma unroll
    for (int m = 0; m < 4; ++m)
#pragma unroll
        for (int n = 0; n < 4; ++n) { f32x4 z = {0.f, 0.f, 0.f, 0.f}; acc[m][n] = z; }

#define STAGE_A(T, BUFI) do {                                         \
    const int _k = (T) * BK;                                          \
    _Pragma("unroll")                                                 \
    for (int g = 0; g < 2; ++g)                                       \
        gload16(aptr[g] + _k, &lds[(BUFI)][g * 64 + wid * 16][0]);    \
} while (0)
#define STAGE_B(T, BUFI) do {                                         \
    const int _k = (T) * BK;                                          \
    _Pragma("unroll")                                                 \
    for (int g = 0; g < 2; ++g)                                       \
        gload16(bptr[g] + _k, &lds[(BUFI)][128 + g * 64 + wid * 16][0]); \
} while (0)

    const int fr    = (l16 ^ (l16 >> 2)) & 3;
    const int rslot = (lhi ^ fr) * 8;                           // ushort offset

    const int NT = DIM / BK;                                    // 32
    STAGE_A(0, 0); STAGE_B(0, 0);
    STAGE_A(1, 1); STAGE_B(1, 1);
    STAGE_A(2, 2); STAGE_B(2, 2);
    asm volatile("s_waitcnt vmcnt(8)" ::: "memory");            // tile 0 landed
    __builtin_amdgcn_s_barrier();

    for (int t = 0; t < NT; ++t) {
        const int c = t & 3;
        const ushort* base = &lds[c][0][0];
        // ---- phase 0: A(m0,m1) + B(all), stage A(t+3), MFMA m0,m1 x n ----
        bf16x8 af0 = *(const bf16x8*)(base + (wr + 0 * 16 + l16) * BK + rslot);
        bf16x8 af1 = *(const bf16x8*)(base + (wr + 1 * 16 + l16) * BK + rslot);
        bf16x8 bfr[4];
#pragma unroll
        for (int n = 0; n < 4; ++n)
            bfr[n] = *(const bf16x8*)(base + (128 + wc + n * 16 + l16) * BK + rslot);
        if (t + 3 < NT) STAGE_A(t + 3, (t + 3) & 3);
        __builtin_amdgcn_s_barrier();
        asm volatile("s_waitcnt lgkmcnt(0)" ::: "memory");
        __builtin_amdgcn_s_setprio(1);
#pragma unroll
        for (int n = 0; n < 4; ++n)
            acc[0][n] = __builtin_amdgcn_mfma_f32_16x16x32_bf16(af0, bfr[n], acc[0][n], 0, 0, 0);
#pragma unroll
        for (int n = 0; n < 4; ++n)
            acc[1][n] = __builtin_amdgcn_mfma_f32_16x16x32_bf16(af1, bfr[n], acc[1][n], 0, 0, 0);
        __builtin_amdgcn_s_setprio(0);
        __builtin_amdgcn_s_barrier();
        // ---- phase 1: A(m2,m3), stage B(t+3), MFMA m2,m3 x n, counted wait --
        bf16x8 af2 = *(const bf16x8*)(base + (wr + 2 * 16 + l16) * BK + rslot);
        bf16x8 af3 = *(const bf16x8*)(base + (wr + 3 * 16 + l16) * BK + rslot);
        if (t + 3 < NT) STAGE_B(t + 3, (t + 3) & 3);
        __builtin_amdgcn_s_barrier();
        asm volatile("s_waitcnt lgkmcnt(0)" ::: "memory");
        __builtin_amdgcn_s_setprio(1);
#pragma unroll
        for (int n = 0; n < 4; ++n)
            acc[2][n] = __builtin_amdgcn_mfma_f32_16x16x32_bf16(af2, bfr[n], acc[2][n], 0, 0, 0);
#pragma unroll
        for (int n = 0; n < 4; ++n)
            acc[3][n] = __builtin_amdgcn_mfma_f32_16x16x32_bf16(af3, bfr[n], acc[3][n], 0, 0, 0);
        __builtin_amdgcn_s_setprio(0);
        if (t < NT - 3)       asm volatile("s_waitcnt vmcnt(8)" ::: "memory");
        else if (t == NT - 3) asm volatile("s_waitcnt vmcnt(4)" ::: "memory");
        else                  asm volatile("s_waitcnt vmcnt(0)" ::: "memory");
        __builtin_amdgcn_s_barrier();
    }
#undef STAGE_A
#undef STAGE_B

    // epilogue: out += w * (acc + be); exactly 2 commutative adds per element
    float bev[4];
#pragma unroll
    for (int n = 0; n < 4; ++n) bev[n] = be[(size_t)e * DIM + c0 + wc + n * 16 + l16];
#pragma unroll
    for (int m = 0; m < 4; ++m) {
#pragma unroll
        for (int r = 0; r < 4; ++r) {
            int rl = wr + m * 16 + lhi * 4 + r;
            if (rl < nrowsv) {
                int   gr = rows[rl];
                float w  = wrow[rl];
                float* op = out + (size_t)gr * DIM + c0 + wc;
#pragma unroll
                for (int n = 0; n < 4; ++n)
                    atomicAdd(&op[n * 16 + l16], w * (acc[m][n][r] + bev[n]));
            }
        }
    }
}

extern "C" void kernel_launch(void* const* d_in, const int* in_sizes, int n_in,
                              void* d_out, int out_size, void* d_ws, size_t ws_size,
                              hipStream_t stream) {
    const float* x     = (const float*)d_in[0];
    const float* noise = (const float*)d_in[1];
    const float* Wg    = (const float*)d_in[2];
    const float* Wn    = (const float*)d_in[3];
    const float* We    = (const float*)d_in[4];
    const float* be    = (const float*)d_in[5];
    float* out = (float*)d_out;

    char* w = (char*)d_ws;
    size_t off = 256;
    int*      cnt   = (int*)w;
    int*      idxl  = (int*)(w + off);      off += (size_t)2 * NE * NR * 4;   // 256 KB
    float*    wl    = (float*)(w + off);    off += (size_t)2 * NE * NR * 4;   // 256 KB
    uint32_t* eid   = (uint32_t*)(w + off); off += (size_t)NR * 4;            // 16 KB
    float2*   wpair = (float2*)(w + off);   off += (size_t)NR * 8;            // 32 KB
    off = (off + 255) & ~(size_t)255;
    float*  WT  = (float*)(w + off);  off += (size_t)16 * DIM * 4;            // 64 KB
    ushort* xbf = (ushort*)(w + off); off += (size_t)NR * DIM * 2;            // 8 MB
    ushort* WeT = (ushort*)(w + off); off += (size_t)NE * DIM * DIM * 2;      // 16 MB

    k1_prep<<<520, 256, 0, stream>>>(Wg, Wn, WT, out);
    k2_main<<<3072, 256, 0, stream>>>(We, WeT, x, noise, WT, xbf, eid, wpair);
    bucket_build<<<NE, 1024, 0, stream>>>(eid, wpair, cnt, idxl, wl);
    moe_gemm<<<72 * 8, 256, 0, stream>>>(xbf, WeT, be, cnt, idxl, wl, out);
}

// Round 10
// 94.694 us; speedup vs baseline: 1.0111x; 1.0111x over previous
//
#include <hip/hip_runtime.h>
#include <hip/hip_bf16.h>
#include <stdint.h>

#define NR   4096
#define DIM  1024
#define NE   8
#define BM   256
#define BN   256
#define BK   32
#define NT   (DIM / BK)          // 32 K-tiles
#define SLOT 16384               // ushorts per ring slot (A 8192 + B 8192)

typedef __attribute__((ext_vector_type(8))) short  bf16x8;
typedef __attribute__((ext_vector_type(8))) ushort u16x8;
typedef __attribute__((ext_vector_type(4))) float  f32x4;

__device__ __forceinline__ ushort f2bf(float f) {
    union { __hip_bfloat16 h; ushort u; } cv;
    cv.h = __float2bfloat16(f);   // RNE
    return cv.u;
}

__device__ __forceinline__ void gload16(const void* g, void* l) {
    __builtin_amdgcn_global_load_lds(
        (const __attribute__((address_space(1))) unsigned int*)g,
        (__attribute__((address_space(3))) unsigned int*)l, 16, 0, 0);
}

// ---------------- K1: WT transpose (blocks 0..7) + zero out (blocks 8..519) --
__global__ __launch_bounds__(256)
void k1_prep(const float* __restrict__ Wg, const float* __restrict__ Wn,
             float* __restrict__ WT, float* __restrict__ out) {
    const int tid = threadIdx.x;
    if (blockIdx.x < 8) {
        const int k    = blockIdx.x * 128 + (tid >> 1);
        const int half = tid & 1;
        const float* src = half ? Wn : Wg;
        const float4* s4 = (const float4*)(src + (size_t)k * NE);
        float4 a = s4[0], b = s4[1];
        float* d = WT + (size_t)half * 8 * DIM;
        d[(size_t)0 * DIM + k] = a.x; d[(size_t)1 * DIM + k] = a.y;
        d[(size_t)2 * DIM + k] = a.z; d[(size_t)3 * DIM + k] = a.w;
        d[(size_t)4 * DIM + k] = b.x; d[(size_t)5 * DIM + k] = b.y;
        d[(size_t)6 * DIM + k] = b.z; d[(size_t)7 * DIM + k] = b.w;
    } else {
        const int vb = blockIdx.x - 8;
        float4 z = {0.f, 0.f, 0.f, 0.f};
        for (int i = vb * 256 + tid; i < NR * DIM / 4; i += 512 * 256)
            ((float4*)out)[i] = z;
    }
}

// ---------------- K2: We convert+transpose (blocks 0..2047) | gate (2048..3071)
__global__ __launch_bounds__(256)
void k2_main(const float* __restrict__ We, ushort* __restrict__ WeT,
             const float* __restrict__ x, const float* __restrict__ noise,
             const float* __restrict__ WT, ushort* __restrict__ xbf,
             uint32_t* __restrict__ eid, float2* __restrict__ wpair) {
    __shared__ float smem[64 * 68];
    const int tid = threadIdx.x;
    if (blockIdx.x < 2048) {
        const int b  = blockIdx.x;
        const int e  = b >> 8, kt = (b >> 4) & 15, ct = b & 15;
        const float* src = We + ((size_t)e * DIM + (size_t)kt * 64) * DIM + ct * 64;
#pragma unroll
        for (int j = 0; j < 4; ++j) {
            int idx = tid + j * 256;
            int r = idx >> 4, c4 = idx & 15;
            *(float4*)&smem[r * 68 + c4 * 4] = *(const float4*)(src + (size_t)r * DIM + c4 * 4);
        }
        __syncthreads();
        ushort* dst = WeT + ((size_t)e * DIM + (size_t)ct * 64) * DIM + kt * 64;
#pragma unroll
        for (int j = 0; j < 2; ++j) {
            int u = tid + j * 256;
            int c = u >> 3, ch = u & 7;
            ushort tmp[8];
#pragma unroll
            for (int q = 0; q < 8; ++q) tmp[q] = f2bf(smem[(ch * 8 + q) * 68 + c]);
            *(u16x8*)(dst + (size_t)c * DIM + ch * 8) = *(u16x8*)tmp;
        }
    } else {
        const int w = tid >> 6, l = tid & 63;
        const int row = (blockIdx.x - 2048) * 4 + w;
        const float* xr = x + (size_t)row * DIM;

        float4 xv[4];
#pragma unroll
        for (int q = 0; q < 4; ++q) xv[q] = *(const float4*)(xr + q * 256 + l * 4);
#pragma unroll
        for (int q = 0; q < 4; ++q) {
            ushort4 xb;
            xb.x = f2bf(xv[q].x); xb.y = f2bf(xv[q].y);
            xb.z = f2bf(xv[q].z); xb.w = f2bf(xv[q].w);
            *(ushort4*)(xbf + (size_t)row * DIM + q * 256 + l * 4) = xb;
        }

        float acc[16];
#pragma unroll
        for (int u = 0; u < 16; ++u) {
            const float* wr_ = WT + (size_t)u * DIM + l * 4;
            float s = 0.f;
#pragma unroll
            for (int q = 0; q < 4; ++q) {
                float4 wv = *(const float4*)(wr_ + q * 256);
                s += xv[q].x * wv.x + xv[q].y * wv.y + xv[q].z * wv.z + xv[q].w * wv.w;
            }
            acc[u] = s;
        }
#pragma unroll
        for (int u = 0; u < 16; ++u) smem[(w * 64 + l) * 17 + u] = acc[u];
        asm volatile("s_waitcnt lgkmcnt(0)" ::: "memory");
        const int c = l >> 4, u = l & 15;
        float v = 0.f;
#pragma unroll
        for (int i = 0; i < 16; ++i) v += smem[(w * 64 + c * 16 + i) * 17 + u];
        v += __shfl_xor(v, 16, 64);
        v += __shfl_xor(v, 32, 64);

        const int e = l & 7;
        float ag = __shfl(v, e, 64);
        float an = __shfl(v, e + 8, 64);
        float sp = (an > 0.f) ? (an + log1pf(expf(-an))) : log1pf(expf(an));
        float H  = ag + noise[e] * sp;

        float Hh[8];
#pragma unroll
        for (int k = 0; k < 8; ++k) Hh[k] = __shfl(H, k, 64);
        if (l == 0) {
            int e0 = 0; float v0 = Hh[0];
#pragma unroll
            for (int k = 1; k < 8; ++k) if (Hh[k] > v0) { v0 = Hh[k]; e0 = k; }
            int e1 = -1; float v1 = 0.f;
#pragma unroll
            for (int k = 0; k < 8; ++k)
                if (k != e0 && (e1 < 0 || Hh[k] > v1)) { v1 = Hh[k]; e1 = k; }
            float rr = expf(v1 - v0);
            float w0 = 1.f / (1.f + rr), w1 = 1.f - w0;
            eid[row] = (uint32_t)e0 | ((uint32_t)e1 << 8);
            float2 wp; wp.x = w0; wp.y = w1;
            wpair[row] = wp;
        }
    }
}

// ---------------- bucket build: merged per-expert buckets (8) ---------------
__global__ __launch_bounds__(1024)
void bucket_build(const uint32_t* __restrict__ eid, const float2* __restrict__ wpair,
                  int* __restrict__ cnt, int* __restrict__ idxl, float* __restrict__ wl) {
    const int ex = blockIdx.x;              // 0..7
    __shared__ int base;
    __shared__ int wsum[16];
    if (threadIdx.x == 0) base = 0;
    const int wid = threadIdx.x >> 6, lane = threadIdx.x & 63;
    int* bidx = idxl + (size_t)ex * NR;
    float* bwl = wl + (size_t)ex * NR;

    for (int c0 = 0; c0 < NR; c0 += 1024) {
        const int row = c0 + threadIdx.x;
        const uint32_t em = eid[row];
        const bool m0 = (int)(em & 255u) == ex;
        const bool m1 = (int)((em >> 8) & 255u) == ex;
        const bool m = m0 || m1;
        const unsigned long long bal = __ballot(m);
        if (lane == 0) wsum[wid] = __popcll(bal);
        __syncthreads();
        int wbase = base;
        for (int i = 0; i < wid; ++i) wbase += wsum[i];
        const int pos = wbase + __popcll(bal & ((1ull << lane) - 1ull));
        if (m) {
            bidx[pos] = row;
            float2 wp = wpair[row];
            bwl[pos]  = m0 ? wp.x : wp.y;
        }
        __syncthreads();
        if (threadIdx.x == 0) {
            int s = 0;
#pragma unroll
            for (int i = 0; i < 16; ++i) s += wsum[i];
            base += s;
        }
        __syncthreads();
    }
    if (threadIdx.x == 0) cnt[ex] = base;
}

// ---------------- grouped expert GEMM: 256x256, 8-phase-style, ring-3 -------
// 8 waves (2M x 4N), BK=32, 2 phases/tile x 16 MFMA, counted vmcnt(4),
// raw s_barrier, setprio around MFMA. 96 KB dynamic LDS -> 1 block/CU.
__global__ __launch_bounds__(512, 2)
void moe_gemm(const ushort* __restrict__ xbf, const ushort* __restrict__ WeT,
              const float* __restrict__ be, const int* __restrict__ cnt,
              const int* __restrict__ idxl, const float* __restrict__ wl,
              float* __restrict__ out) {
    extern __shared__ ushort lds[];          // 3 * SLOT ushorts = 96 KB

    const int q8 = gridDim.x >> 3;
    const int W  = (blockIdx.x & 7) * q8 + (blockIdx.x >> 3);
    const int item = W >> 2, cT = W & 3;

    int bucket = -1, tile = 0, accp = 0;
#pragma unroll
    for (int b = 0; b < NE; ++b) {
        int t = (cnt[b] + BM - 1) >> 8;
        if (bucket < 0 && item < accp + t) { bucket = b; tile = item - accp; }
        accp += t;
    }
    if (bucket < 0) return;
    const int count  = cnt[bucket];
    const int nrows  = min(BM, count - tile * BM);
    const int e  = bucket;
    const int c0 = cT * BN;
    const int*   rows = idxl + (size_t)bucket * NR + tile * BM;
    const float* wrow = wl   + (size_t)bucket * NR + tile * BM;

    const int tid = threadIdx.x, wid = tid >> 6, lane = tid & 63;
    const int l16 = lane & 15, lhi = lane >> 4;
    const int widM = wid >> 2, widN = wid & 3;        // 2 x 4 wave grid
    const int arow = widM * 128, bcol = widN * 64;

    // ---- staging sources (1 gload16/thread per half-tile) ----
    // thread -> (row = tid>>2, chunk = tid&3); source chunk ^= f(row)
    const int srow = tid >> 2;
    const int csrc = (((tid & 3) ^ (((tid >> 2) ^ (tid >> 4)) & 3)) * 8);
    const ushort* a0 = xbf + (size_t)rows[min(srow,       nrows - 1)] * DIM + csrc;
    const ushort* a1 = xbf + (size_t)rows[min(128 + srow, nrows - 1)] * DIM + csrc;
    const ushort* b0 = WeT + ((size_t)(e * DIM + c0 + srow))       * DIM + csrc;
    const ushort* b1 = WeT + ((size_t)(e * DIM + c0 + 128 + srow)) * DIM + csrc;
    const int dA0 = wid * 512, dA1 = 4096 + wid * 512;
    const int dB0 = 8192 + wid * 512, dB1 = 8192 + 4096 + wid * 512;

    // ---- read-side swizzle (verified R8 pattern; wave bases are x16) ----
    const int fr  = (l16 ^ (l16 >> 2)) & 3;
    const int rch = (lhi ^ fr) * 8;                   // ushort offset in 32-row

    f32x4 acc[8][4];
#pragma unroll
    for (int m = 0; m < 8; ++m)
#pragma unroll
        for (int n = 0; n < 4; ++n) { f32x4 z = {0.f, 0.f, 0.f, 0.f}; acc[m][n] = z; }

    // prologue: tiles 0 -> slot 0, 1 -> slot 1 (4 loads/thread each)
    gload16(a0,      lds + 0 * SLOT + dA0); gload16(a1,      lds + 0 * SLOT + dA1);
    gload16(b0,      lds + 0 * SLOT + dB0); gload16(b1,      lds + 0 * SLOT + dB1);
    gload16(a0 + BK, lds + 1 * SLOT + dA0); gload16(a1 + BK, lds + 1 * SLOT + dA1);
    gload16(b0 + BK, lds + 1 * SLOT + dB0); gload16(b1 + BK, lds + 1 * SLOT + dB1);
    asm volatile("s_waitcnt vmcnt(4)" ::: "memory");  // tile 0 landed
    __builtin_amdgcn_s_barrier();

    int cur = 0, stg = 2;
    for (int t = 0; t < NT; ++t) {
        const ushort* Ab = lds + cur * SLOT;
        const ushort* Bb = lds + cur * SLOT + 8192;
        const bool pf = (t + 2 < NT);
        const int  ko = (t + 2) * BK;

        // ===== phase 0: read A m0..3 + B all, stage A halves of t+2 =====
        bf16x8 af[4], bfr[4];
#pragma unroll
        for (int m = 0; m < 4; ++m)
            af[m] = *(const bf16x8*)(Ab + (arow + m * 16 + l16) * BK + rch);
#pragma unroll
        for (int n = 0; n < 4; ++n)
            bfr[n] = *(const bf16x8*)(Bb + (bcol + n * 16 + l16) * BK + rch);
        if (pf) {
            gload16(a0 + ko, lds + stg * SLOT + dA0);
            gload16(a1 + ko, lds + stg * SLOT + dA1);
        }
        __builtin_amdgcn_s_barrier();
        asm volatile("s_waitcnt lgkmcnt(0)" ::: "memory");
        __builtin_amdgcn_s_setprio(1);
#pragma unroll
        for (int m = 0; m < 4; ++m)
#pragma unroll
            for (int n = 0; n < 4; ++n)
                acc[m][n] = __builtin_amdgcn_mfma_f32_16x16x32_bf16(af[m], bfr[n], acc[m][n], 0, 0, 0);
        __builtin_amdgcn_s_setprio(0);
        __builtin_amdgcn_s_barrier();

        // ===== phase 1: read A m4..7, stage B halves of t+2, reuse bfr =====
#pragma unroll
        for (int m = 0; m < 4; ++m)
            af[m] = *(const bf16x8*)(Ab + (arow + (m + 4) * 16 + l16) * BK + rch);
        if (pf) {
            gload16(b0 + ko, lds + stg * SLOT + dB0);
            gload16(b1 + ko, lds + stg * SLOT + dB1);
        }
        __builtin_amdgcn_s_barrier();
        asm volatile("s_waitcnt lgkmcnt(0)" ::: "memory");
        __builtin_amdgcn_s_setprio(1);
#pragma unroll
        for (int m = 0; m < 4; ++m)
#pragma unroll
            for (int n = 0; n < 4; ++n)
                acc[m + 4][n] = __builtin_amdgcn_mfma_f32_16x16x32_bf16(af[m], bfr[n], acc[m + 4][n], 0, 0, 0);
        __builtin_amdgcn_s_setprio(0);
        if (pf) asm volatile("s_waitcnt vmcnt(4)" ::: "memory");  // t+1 landed
        else    asm volatile("s_waitcnt vmcnt(0)" ::: "memory");
        __builtin_amdgcn_s_barrier();

        cur = (cur == 2) ? 0 : cur + 1;
        stg = (stg == 2) ? 0 : stg + 1;
    }

    // ---- epilogue: out += w * (acc + be); exactly 2 commutative adds/elem ----
    float bev[4];
#pragma unroll
    for (int n = 0; n < 4; ++n) bev[n] = be[(size_t)e * DIM + c0 + bcol + n * 16 + l16];
#pragma unroll
    for (int m = 0; m < 8; ++m) {
#pragma unroll
        for (int r = 0; r < 4; ++r) {
            int rl = arow + m * 16 + lhi * 4 + r;
            if (rl < nrows) {
                int   gr = rows[rl];
                float w  = wrow[rl];
                float* op = out + (size_t)gr * DIM + c0 + bcol;
#pragma unroll
                for (int n = 0; n < 4; ++n)
                    atomicAdd(&op[n * 16 + l16], w * (acc[m][n][r] + bev[n]));
            }
        }
    }
}

extern "C" void kernel_launch(void* const* d_in, const int* in_sizes, int n_in,
                              void* d_out, int out_size, void* d_ws, size_t ws_size,
                              hipStream_t stream) {
    const float* x     = (const float*)d_in[0];
    const float* noise = (const float*)d_in[1];
    const float* Wg    = (const float*)d_in[2];
    const float* Wn    = (const float*)d_in[3];
    const float* We    = (const float*)d_in[4];
    const float* be    = (const float*)d_in[5];
    float* out = (float*)d_out;

    char* w = (char*)d_ws;
    size_t off = 256;
    int*      cnt   = (int*)w;
    int*      idxl  = (int*)(w + off);      off += (size_t)2 * NE * NR * 4;
    float*    wl    = (float*)(w + off);    off += (size_t)2 * NE * NR * 4;
    uint32_t* eid   = (uint32_t*)(w + off); off += (size_t)NR * 4;
    float2*   wpair = (float2*)(w + off);   off += (size_t)NR * 8;
    off = (off + 255) & ~(size_t)255;
    float*  WT  = (float*)(w + off);  off += (size_t)16 * DIM * 4;
    ushort* xbf = (ushort*)(w + off); off += (size_t)NR * DIM * 2;
    ushort* WeT = (ushort*)(w + off); off += (size_t)NE * DIM * DIM * 2;

    // allow 96 KB dynamic LDS (idempotent, non-stream call; safe under capture)
    (void)hipFuncSetAttribute((const void*)moe_gemm,
                              hipFuncAttributeMaxDynamicSharedMemorySize,
                              3 * SLOT * (int)sizeof(ushort));

    k1_prep<<<520, 256, 0, stream>>>(Wg, Wn, WT, out);
    k2_main<<<3072, 256, 0, stream>>>(We, WeT, x, noise, WT, xbf, eid, wpair);
    bucket_build<<<NE, 1024, 0, stream>>>(eid, wpair, cnt, idxl, wl);
    moe_gemm<<<160, 512, 3 * SLOT * sizeof(ushort), stream>>>(xbf, WeT, be, cnt, idxl, wl, out);
}